// Round 14
// baseline (83.079 us; speedup 1.0000x reference)
//
#include <hip/hip_runtime.h>
#include <math.h>

#define H 28
#define N 784
#define B 32
#define T 25
#define NPAD 1024
#define CH 16
#define MEDGE 1536
#define NOFF 3025   // 55*55 lattice offsets

// ============================================================
// Compile-time ordered offset table: sorted by (integer d2, dr, dc).
// Row-independent neighbor order (validated rounds 10-13, absmax 0).
// ============================================================
struct OffTable { unsigned short v[NOFF]; };
constexpr OffTable make_offs() {
    OffTable t{};
    int cnt[1459] = {};
    for (int dr = -27; dr <= 27; ++dr)
        for (int dc = -27; dc <= 27; ++dc)
            cnt[dr * dr + dc * dc]++;
    int base[1459] = {};
    int acc = 0;
    for (int d = 0; d <= 1458; ++d) { base[d] = acc; acc += cnt[d]; }
    for (int dr = -27; dr <= 27; ++dr)
        for (int dc = -27; dc <= 27; ++dc) {
            int d2 = dr * dr + dc * dc;
            t.v[base[d2]++] = (unsigned short)(((dr + 27) << 6) | (dc + 27));
        }
    return t;
}
__device__ __constant__ OffTable OFF_TABLE = make_offs();

// ---- numpy linspace replication (float64) ----
__device__ __forceinline__ double coord_r_f(int i) {
    if (i == H - 1) return 0.0;
    return 224.0 + (double)i * ((0.0 - 224.0) / 27.0);
}
__device__ __forceinline__ double coord_c_f(int j) {
    if (j == H - 1) return 224.0;
    return (double)j * (224.0 / 27.0);
}

__device__ __forceinline__ unsigned long long shfl_xor64(unsigned long long v, int m) {
    int lo = __shfl_xor((int)(unsigned)v, m, 64);
    int hi = __shfl_xor((int)(unsigned)(v >> 32), m, 64);
    return ((unsigned long long)(unsigned)hi << 32) | (unsigned)lo;
}

// ============================================================
// K1: per-row filter-compaction, 3 barriers (r13, passing).
// ============================================================
__global__ __launch_bounds__(256) void build_lists_kernel(
        float* __restrict__ d2s, unsigned short* __restrict__ sidx) {
    __shared__ double crtab[H], cctab[H];
    __shared__ float cd2[N];
    __shared__ unsigned short cjj[N];
    __shared__ unsigned long long wmask[48];
    __shared__ int wbase[48];
    const int i = blockIdx.x, tid = threadIdx.x, lane = tid & 63;
    const int w = tid >> 6;
    if (tid < H) { crtab[tid] = coord_r_f(tid); cctab[tid] = coord_c_f(tid); }
    const int ri = i / H, ci = i % H;
    unsigned validm = 0;
    #pragma unroll
    for (int c = 0; c < 12; ++c) {
        int p = c * 256 + tid;
        bool valid = false;
        if (p < NOFF) {
            unsigned o = OFF_TABLE.v[p];
            int rj = ri + (int)(o >> 6) - 27;
            int cj_ = ci + (int)(o & 63u) - 27;
            valid = ((unsigned)rj < (unsigned)H) && ((unsigned)cj_ < (unsigned)H);
        }
        unsigned long long m = __ballot(valid);
        if (valid) validm |= (1u << c);
        if (lane == 0) wmask[c * 4 + w] = m;
    }
    __syncthreads();
    if (w == 0) {
        int cnt = (lane < 48) ? __popcll(wmask[lane]) : 0;
        int inc = cnt;
        #pragma unroll
        for (int off = 1; off < 64; off <<= 1) {
            int n = __shfl_up(inc, off, 64);
            if (lane >= off) inc += n;
        }
        if (lane < 48) wbase[lane] = inc - cnt;   // exclusive prefix
    }
    __syncthreads();
    const double rri = crtab[ri], cci = cctab[ci];
    const unsigned long long ltmask = (lane == 0) ? 0ull : (~0ull >> (64 - lane));
    #pragma unroll
    for (int c = 0; c < 12; ++c) {
        if (validm & (1u << c)) {
            int p = c * 256 + tid;
            unsigned o = OFF_TABLE.v[p];
            int rj = ri + (int)(o >> 6) - 27;
            int cj_ = ci + (int)(o & 63u) - 27;
            int pos = wbase[c * 4 + w] + __popcll(wmask[c * 4 + w] & ltmask);
            double ddr = rri - crtab[rj];
            double ddc = cci - cctab[cj_];
            cd2[pos] = (float)(ddr * ddr + ddc * ddc);
            cjj[pos] = (unsigned short)(rj * H + cj_);
        }
    }
    __syncthreads();
    for (int k = tid; k < N; k += 256) {
        d2s[(size_t)i * N + k]  = cd2[k];
        sidx[(size_t)i * N + k] = cjj[k];
    }
}

// ============================================================
// K2 (fused): DTM walk + argsort + basins + tiny UF + landscapes.
// One 1024-thread block per (m0, b) problem.
// ============================================================
__device__ __forceinline__ int pf_find(volatile float2* pf, int x, unsigned& fbits) {
    float2 e;
    e.x = pf[x].x; e.y = pf[x].y;
    int p = __float_as_int(e.y);
    while (p != x) {
        float2 ep;
        ep.x = pf[p].x; ep.y = pf[p].y;
        int gp = __float_as_int(ep.y);
        if (gp != p) { pf[x].x = ep.x; pf[x].y = ep.y; }   // path halving
        x = p; e = ep; p = gp;
    }
    fbits = __float_as_uint(e.x);
    return x;
}

__device__ __forceinline__ unsigned long long vkey(const float* fv, int u) {
    return (((unsigned long long)__float_as_uint(fv[u])) << 10) | (unsigned long long)u;
}

__global__ __launch_bounds__(1024) void dtm_topo_kernel(
        const float* __restrict__ x,
        const float* __restrict__ d2s,
        const unsigned short* __restrict__ sidx,
        float* __restrict__ feat) {
    __shared__ float lw[N];
    __shared__ unsigned long long skey64[NPAD];
    __shared__ float fv[N];
    __shared__ float dv[N];
    __shared__ float2 pf_s[N];
    __shared__ short pd[N];
    __shared__ short labA[N], labB[N];
    __shared__ unsigned ev[MEDGE];
    __shared__ int wsum[32];
    __shared__ float m0W_s;
    volatile float2* pf = pf_s;
    const int prob = blockIdx.x, tid = threadIdx.x, lane = tid & 63, wid = tid >> 6;
    const int b = prob & 31, mi = prob >> 5;
    const float m0 = mi ? 0.2f : 0.05f;

    // ---- weights + total mass (wave reduce, 2 barriers) ----
    {
        float s = 0.f;
        if (tid < N) { float v = x[b * N + tid]; lw[tid] = v; s = v; }
        #pragma unroll
        for (int off = 32; off > 0; off >>= 1) s += __shfl_down(s, off, 64);
        if (lane == 0) wsum[wid] = __float_as_int(s);
        __syncthreads();
        if (wid == 0) {
            float v = (lane < 16) ? __int_as_float(wsum[lane]) : 0.f;
            #pragma unroll
            for (int off = 8; off > 0; off >>= 1) v += __shfl_down(v, off, 64);
            if (lane == 0) m0W_s = m0 * v;
        }
        __syncthreads();
    }
    const float m0W = m0W_s;

    // ---- DTM: 1 pixel/thread, early-exit walk of presorted rows ----
    if (tid < N) {
        const float* d2r = d2s + (size_t)tid * N;
        const unsigned short* idr = sidx + (size_t)tid * N;
        float cum = 0.f, acc = 0.f;
        for (int k0 = 0; k0 < N; k0 += CH) {
            float d2c[CH]; int idc[CH];
            #pragma unroll
            for (int c = 0; c < CH; ++c) { d2c[c] = d2r[k0 + c]; idc[c] = idr[k0 + c]; }
            float swc[CH];
            #pragma unroll
            for (int c = 0; c < CH; ++c) swc[c] = lw[idc[c]];
            #pragma unroll
            for (int c = 0; c < CH; ++c) {
                float rem = m0W - cum;
                float contrib = fminf(fmaxf(rem, 0.f), swc[c]);
                acc += contrib * d2c[c];
                cum += swc[c];
            }
            if (cum >= m0W) break;   // all later contribs are exactly 0
        }
        fv[tid] = sqrtf(fmaxf(acc / m0W, 1e-12f));
    }
    // ---- sort keys ----
    skey64[tid] = 0;   // placeholder; set below after fv visible
    __syncthreads();
    skey64[tid] = (tid < N)
        ? ((((unsigned long long)__float_as_uint(fv[tid])) << 10) | (unsigned long long)tid)
        : ~0ull;
    __syncthreads();

    // ---- hybrid bitonic on waves 0-7 (barriers outside guard) ----
    {
        const bool act = (wid < 8);
        const int idx0 = (wid & 7) * 128 + lane;
        const int idx1 = idx0 + 64;
        unsigned long long e0 = 0, e1 = 0;
        if (act) { e0 = skey64[idx0]; e1 = skey64[idx1]; }
        for (int k = 2; k <= NPAD; k <<= 1) {
            for (int j = k >> 1; j > 0; j >>= 1) {
                if (j >= 128) {
                    if (act) { skey64[idx0] = e0; skey64[idx1] = e1; }
                    __syncthreads();
                    if (act) {
                        unsigned long long p0 = skey64[idx0 ^ j];
                        unsigned long long p1 = skey64[idx1 ^ j];
                        bool up0 = ((idx0 & k) == 0), lo0 = ((idx0 & j) == 0);
                        bool up1 = ((idx1 & k) == 0), lo1 = ((idx1 & j) == 0);
                        e0 = (up0 == lo0) ? (p0 < e0 ? p0 : e0) : (p0 > e0 ? p0 : e0);
                        e1 = (up1 == lo1) ? (p1 < e1 ? p1 : e1) : (p1 > e1 ? p1 : e1);
                    }
                    __syncthreads();
                } else if (act) {
                    if (j == 64) {
                        bool up = ((idx0 & k) == 0);
                        unsigned long long mn = e0 < e1 ? e0 : e1;
                        unsigned long long mx = e0 < e1 ? e1 : e0;
                        e0 = up ? mn : mx; e1 = up ? mx : mn;
                    } else {
                        unsigned long long p0 = shfl_xor64(e0, j);
                        unsigned long long p1 = shfl_xor64(e1, j);
                        bool lo = ((lane & j) == 0);
                        bool up0 = ((idx0 & k) == 0);
                        bool up1 = ((idx1 & k) == 0);
                        e0 = (up0 == lo) ? (p0 < e0 ? p0 : e0) : (p0 > e0 ? p0 : e0);
                        e1 = (up1 == lo) ? (p1 < e1 ? p1 : e1) : (p1 > e1 ? p1 : e1);
                    }
                }
            }
        }
        if (act) { skey64[idx0] = e0; skey64[idx1] = e1; }
    }
    __syncthreads();

    // ---- pf/pd init + descent pointers (min-key neighbor) ----
    if (tid < N) {
        int v = tid;
        pf_s[v] = make_float2(fv[v], __int_as_float(v));
        pd[v] = (short)v;
        int row = v / H, col = v % H;
        unsigned long long bk = vkey(fv, v); int bestn = v;
        if (row > 0)     { unsigned long long kk = vkey(fv, v - H); if (kk < bk) { bk = kk; bestn = v - H; } }
        if (row < H - 1) { unsigned long long kk = vkey(fv, v + H); if (kk < bk) { bk = kk; bestn = v + H; } }
        if (col > 0)     { unsigned long long kk = vkey(fv, v - 1); if (kk < bk) { bk = kk; bestn = v - 1; } }
        if (col < H - 1) { unsigned long long kk = vkey(fv, v + 1); if (kk < bk) { bk = kk; bestn = v + 1; } }
        labA[v] = (short)bestn;
    }
    __syncthreads();
    // ---- pointer jumping to basin minima ----
    {
        short* lsrc = labA; short* ldst = labB;
        for (int it = 0; it < 10; ++it) {
            if (tid < N) ldst[tid] = lsrc[(int)lsrc[tid]];
            __syncthreads();
            short* t = lsrc; lsrc = ldst; ldst = t;
        }
    }
    const short* lab = labA;   // 10 swaps -> back in labA
    // ---- candidates: 1 sorted rank per thread, ref order ----
    int deg = 0, vq = 1023, lvq = 0;
    {
        int v = (int)(skey64[tid] & 1023ull);
        vq = v;
        if (v < N) {
            unsigned long long kv = skey64[tid];
            int row = v / H, col = v % H;
            int lv = (int)lab[v]; lvq = lv;
            if (row > 0     && vkey(fv, v - H) < kv && (int)lab[v - H] != lv) deg++;
            if (row < H - 1 && vkey(fv, v + H) < kv && (int)lab[v + H] != lv) deg++;
            if (col > 0     && vkey(fv, v - 1) < kv && (int)lab[v - 1] != lv) deg++;
            if (col < H - 1 && vkey(fv, v + 1) < kv && (int)lab[v + 1] != lv) deg++;
        }
    }
    int inc = deg;
    #pragma unroll
    for (int off = 1; off < 64; off <<= 1) {
        int n = __shfl_up(inc, off, 64);
        if (lane >= off) inc += n;
    }
    if (lane == 63) wsum[wid] = inc;
    __syncthreads();
    if (wid == 0) {
        int v = (lane < 16) ? wsum[lane] : 0;
        #pragma unroll
        for (int off = 1; off < 16; off <<= 1) {
            int n = __shfl_up(v, off, 64);
            if (lane >= off) v += n;
        }
        if (lane < 16) wsum[16 + lane] = v;
    }
    __syncthreads();
    int base = (wid ? wsum[16 + wid - 1] : 0) + inc - deg;
    const int mc = wsum[16 + 15];
    if (vq < N && deg) {
        unsigned long long kv = skey64[tid];
        int v = vq;
        int row = v / H, col = v % H;
        int nbs[4] = { v - H, v + H, v - 1, v + 1 };
        bool val[4] = { row > 0, row < H - 1, col > 0, col < H - 1 };
        int pos = base;
        #pragma unroll
        for (int k4 = 0; k4 < 4; ++k4) {
            if (val[k4] && vkey(fv, nbs[k4]) < kv && (int)lab[nbs[k4]] != lvq) {
                ev[pos++] = (unsigned)v | ((unsigned)lvq << 10)
                          | ((unsigned)(int)lab[nbs[k4]] << 20);
            }
        }
    }
    __syncthreads();

    // ---- wave-0 tiny UF over candidates (ballot resolve) ----
    if (tid < 64) {
        const int nch = (mc + 63) >> 6;
        for (int c = 0; c < nch; ++c) {
            int idx = c * 64 + lane;
            unsigned e = (idx < mc) ? ev[idx] : 0u;
            const int uu = (int)(e & 1023u);
            const int bu = (int)((e >> 10) & 1023u);
            const int bw = (int)((e >> 20) & 1023u);
            unsigned fa, fb;
            int ra = pf_find(pf, bu, fa);
            int rb = pf_find(pf, bw, fb);
            int myL = -1, myW = 0; unsigned myWF = 0;
            unsigned long long mask = __ballot(ra != rb);
            while (mask) {
                int j = __builtin_ctzll(mask);
                mask &= mask - 1;
                int s_a = __builtin_amdgcn_readlane(ra, j);
                int s_b = __builtin_amdgcn_readlane(rb, j);
                if (s_a != s_b) {          // uniform
                    unsigned s_fa = (unsigned)__builtin_amdgcn_readlane((int)fa, j);
                    unsigned s_fb = (unsigned)__builtin_amdgcn_readlane((int)fb, j);
                    bool nw = (s_fb < s_fa) || (s_fb == s_fa && s_b < s_a);
                    int s_w = nw ? s_b : s_a;
                    int s_l = nw ? s_a : s_b;
                    unsigned s_wf = nw ? s_fb : s_fa;
                    bool me = (lane == j);
                    myL  = me ? s_l  : myL;
                    myW  = me ? s_w  : myW;
                    myWF = me ? s_wf : myWF;
                    bool ha = (ra == s_l);
                    ra = ha ? s_w : ra; fa = ha ? s_wf : fa;
                    bool hb = (rb == s_l);
                    rb = hb ? s_w : rb; fb = hb ? s_wf : fb;
                }
            }
            if (myL >= 0) {                // losers distinct -> race-free
                pd[myL] = (short)uu;
                pf[myL].x = __uint_as_float(myWF);
                pf[myL].y = __int_as_float(myW);
            }
            __builtin_amdgcn_sched_barrier(0);
        }
        if (lane == 0) {
            unsigned dummy;
            int vmax = (int)(skey64[N - 1] & 1023ull);
            int g = pf_find(pf, (int)lab[vmax], dummy);
            pd[g] = (short)vmax;
        }
    }
    __syncthreads();

    // ---- death values, then landscapes with linear reads ----
    if (tid < N) dv[tid] = fv[(int)pd[tid]];
    __syncthreads();
    for (int t = wid; t < T; t += 16) {
        float tval = (t == T - 1) ? 80.0f : (1.0f + (float)t * (79.0f / 24.0f));
        float m1 = 0.f, m2 = 0.f;
        for (int i = lane; i < N; i += 64) {
            float tv = fminf(tval - fv[i], dv[i] - tval);
            tv = fmaxf(tv, 0.f);
            float lo = fminf(tv, m1);
            m1 = fmaxf(tv, m1);
            m2 = fmaxf(m2, lo);
        }
        #pragma unroll
        for (int off = 32; off > 0; off >>= 1) {
            float o1 = __shfl_down(m1, off, 64);
            float o2 = __shfl_down(m2, off, 64);
            float hi = fmaxf(m1, o1);
            float lo = fminf(m1, o1);
            m2 = fmaxf(fmaxf(m2, o2), lo);
            m1 = hi;
        }
        if (lane == 0) {
            feat[prob * 50 + t]     = m1;
            feat[prob * 50 + T + t] = m2;
        }
    }
}

// ============================================================
// K3: head.
// ============================================================
__global__ void head_kernel(const float* __restrict__ feat,
                            const float* __restrict__ wg1, const float* __restrict__ bg1,
                            const float* __restrict__ wg2, const float* __restrict__ bg2,
                            const float* __restrict__ fcw, const float* __restrict__ fcb,
                            float* __restrict__ out) {
    __shared__ float xc[B * 100];
    const int tid = threadIdx.x;
    for (int e = tid; e < B * 100; e += 256) {
        int b = e / 100, j = e % 100;
        const float* fp; const float* wrow; float bias;
        if (j < 50) { fp = feat + b * 50;       wrow = wg1 + j * 50;        bias = bg1[j]; }
        else        { fp = feat + (B + b) * 50; wrow = wg2 + (j - 50) * 50; bias = bg2[j - 50]; }
        float acc = bias;
        for (int q = 0; q < 50; ++q) acc += fp[q] * wrow[q];
        xc[e] = acc;
    }
    __syncthreads();
    for (int j = tid; j < 100; j += 256) {
        float s = 0.f;
        for (int b = 0; b < B; ++b) s += fabsf(xc[b * 100 + j]);
        out[320 + j] = s;
    }
    for (int e = tid; e < 320; e += 256) {
        int b = e / 10, o = e % 10;
        float acc = fcb[o];
        for (int j = 0; j < 100; ++j)
            acc += fmaxf(xc[b * 100 + j], 0.f) * fcw[o * 100 + j];
        out[e] = acc;
    }
}

extern "C" void kernel_launch(void* const* d_in, const int* in_sizes, int n_in,
                              void* d_out, int out_size, void* d_ws, size_t ws_size,
                              hipStream_t stream) {
    (void)in_sizes; (void)n_in; (void)out_size; (void)ws_size;
    const float* x   = (const float*)d_in[0];
    const float* wg1 = (const float*)d_in[1];
    const float* bg1 = (const float*)d_in[2];
    const float* wg2 = (const float*)d_in[3];
    const float* bg2 = (const float*)d_in[4];
    const float* fcw = (const float*)d_in[5];
    const float* fcb = (const float*)d_in[6];
    float* out = (float*)d_out;

    char* ws = (char*)d_ws;
    float*          d2s    = (float*)ws;                                   // 784*784 f32
    unsigned short* sidx   = (unsigned short*)(ws + (size_t)N * N * 4);    // 784*784 u16
    float*          feat   = (float*)(ws + (size_t)N * N * 6);             // 64*50 f32

    build_lists_kernel<<<dim3(N), dim3(256), 0, stream>>>(d2s, sidx);
    dtm_topo_kernel<<<dim3(64), dim3(1024), 0, stream>>>(x, d2s, sidx, feat);
    head_kernel<<<dim3(1), dim3(256), 0, stream>>>(feat, wg1, bg1, wg2, bg2, fcw, fcb, out);
}

// Round 15
// 74.596 us; speedup vs baseline: 1.1137x; 1.1137x over previous
//
#include <hip/hip_runtime.h>
#include <math.h>

#define H 28
#define N 784
#define B 32
#define T 25
#define NPAD 1024
#define CH 16
#define MEDGE 1536
#define NOFF 3025   // 55*55 lattice offsets

// ============================================================
// Compile-time ordered offset table: sorted by (integer d2, dr, dc).
// Row-independent neighbor order (validated rounds 10-14, absmax 0).
// ============================================================
struct OffTable { unsigned short v[NOFF]; };
constexpr OffTable make_offs() {
    OffTable t{};
    int cnt[1459] = {};
    for (int dr = -27; dr <= 27; ++dr)
        for (int dc = -27; dc <= 27; ++dc)
            cnt[dr * dr + dc * dc]++;
    int base[1459] = {};
    int acc = 0;
    for (int d = 0; d <= 1458; ++d) { base[d] = acc; acc += cnt[d]; }
    for (int dr = -27; dr <= 27; ++dr)
        for (int dc = -27; dc <= 27; ++dc) {
            int d2 = dr * dr + dc * dc;
            t.v[base[d2]++] = (unsigned short)(((dr + 27) << 6) | (dc + 27));
        }
    return t;
}
__device__ __constant__ OffTable OFF_TABLE = make_offs();

// ---- numpy linspace replication (float64) ----
__device__ __forceinline__ double coord_r_f(int i) {
    if (i == H - 1) return 0.0;
    return 224.0 + (double)i * ((0.0 - 224.0) / 27.0);
}
__device__ __forceinline__ double coord_c_f(int j) {
    if (j == H - 1) return 224.0;
    return (double)j * (224.0 / 27.0);
}

__device__ __forceinline__ unsigned long long shfl_xor64(unsigned long long v, int m) {
    int lo = __shfl_xor((int)(unsigned)v, m, 64);
    int hi = __shfl_xor((int)(unsigned)(v >> 32), m, 64);
    return ((unsigned long long)(unsigned)hi << 32) | (unsigned)lo;
}

// ============================================================
// K1: per-row filter-compaction, 3 barriers (r13, passing).
// Also zeroes the topo completion counter (used 2 kernels later).
// ============================================================
__global__ __launch_bounds__(256) void build_lists_kernel(
        float* __restrict__ d2s, unsigned short* __restrict__ sidx,
        int* __restrict__ cnt_g) {
    __shared__ double crtab[H], cctab[H];
    __shared__ float cd2[N];
    __shared__ unsigned short cjj[N];
    __shared__ unsigned long long wmask[48];
    __shared__ int wbase[48];
    const int i = blockIdx.x, tid = threadIdx.x, lane = tid & 63;
    const int w = tid >> 6;
    if (i == 0 && tid == 0) *cnt_g = 0;
    if (tid < H) { crtab[tid] = coord_r_f(tid); cctab[tid] = coord_c_f(tid); }
    const int ri = i / H, ci = i % H;
    unsigned validm = 0;
    #pragma unroll
    for (int c = 0; c < 12; ++c) {
        int p = c * 256 + tid;
        bool valid = false;
        if (p < NOFF) {
            unsigned o = OFF_TABLE.v[p];
            int rj = ri + (int)(o >> 6) - 27;
            int cj_ = ci + (int)(o & 63u) - 27;
            valid = ((unsigned)rj < (unsigned)H) && ((unsigned)cj_ < (unsigned)H);
        }
        unsigned long long m = __ballot(valid);
        if (valid) validm |= (1u << c);
        if (lane == 0) wmask[c * 4 + w] = m;
    }
    __syncthreads();
    if (w == 0) {
        int cnt = (lane < 48) ? __popcll(wmask[lane]) : 0;
        int inc = cnt;
        #pragma unroll
        for (int off = 1; off < 64; off <<= 1) {
            int n = __shfl_up(inc, off, 64);
            if (lane >= off) inc += n;
        }
        if (lane < 48) wbase[lane] = inc - cnt;   // exclusive prefix
    }
    __syncthreads();
    const double rri = crtab[ri], cci = cctab[ci];
    const unsigned long long ltmask = (lane == 0) ? 0ull : (~0ull >> (64 - lane));
    #pragma unroll
    for (int c = 0; c < 12; ++c) {
        if (validm & (1u << c)) {
            int p = c * 256 + tid;
            unsigned o = OFF_TABLE.v[p];
            int rj = ri + (int)(o >> 6) - 27;
            int cj_ = ci + (int)(o & 63u) - 27;
            int pos = wbase[c * 4 + w] + __popcll(wmask[c * 4 + w] & ltmask);
            double ddr = rri - crtab[rj];
            double ddc = cci - cctab[cj_];
            cd2[pos] = (float)(ddr * ddr + ddc * ddc);
            cjj[pos] = (unsigned short)(rj * H + cj_);
        }
    }
    __syncthreads();
    for (int k = tid; k < N; k += 256) {
        d2s[(size_t)i * N + k]  = cd2[k];
        sidx[(size_t)i * N + k] = cjj[k];
    }
}

// ============================================================
// K2: DTM. 4 blocks per problem (256 blocks), 1 pixel/thread,
// early-exit walk of the row-major presorted list. (r12/r13, passing)
// ============================================================
__global__ __launch_bounds__(256) void dtm_kernel(
        const float* __restrict__ x,
        const float* __restrict__ d2s,
        const unsigned short* __restrict__ sidx,
        float* __restrict__ fv_g) {
    __shared__ float lw[N];
    __shared__ float red[256];
    const int blk = blockIdx.x;
    const int prob = blk >> 2, quarter = blk & 3;
    const int b = prob & 31, mi = prob >> 5;
    const float m0 = mi ? 0.2f : 0.05f;
    const int tid = threadIdx.x;
    float s = 0.f;
    for (int j = tid; j < N; j += 256) { float v = x[b * N + j]; lw[j] = v; s += v; }
    red[tid] = s;
    __syncthreads();
    for (int off = 128; off > 0; off >>= 1) {
        if (tid < off) red[tid] += red[tid + off];
        __syncthreads();
    }
    const float m0W = m0 * red[0];
    if (tid < 196) {
        const int i = quarter * 196 + tid;
        const float* d2r = d2s + (size_t)i * N;
        const unsigned short* idr = sidx + (size_t)i * N;
        float cum = 0.f, acc = 0.f;
        for (int k0 = 0; k0 < N; k0 += CH) {
            float d2c[CH]; int idc[CH];
            #pragma unroll
            for (int c = 0; c < CH; ++c) { d2c[c] = d2r[k0 + c]; idc[c] = idr[k0 + c]; }
            float swc[CH];
            #pragma unroll
            for (int c = 0; c < CH; ++c) swc[c] = lw[idc[c]];
            #pragma unroll
            for (int c = 0; c < CH; ++c) {
                float rem = m0W - cum;
                float contrib = fminf(fmaxf(rem, 0.f), swc[c]);
                acc += contrib * d2c[c];
                cum += swc[c];
            }
            if (cum >= m0W) break;   // all later contribs are exactly 0
        }
        fv_g[prob * N + i] = sqrtf(fmaxf(acc / m0W, 1e-12f));
    }
}

// ============================================================
// K3: topo (r13, passing) + atomic-tail head (last block).
// ============================================================
__device__ __forceinline__ int pf_find(volatile float2* pf, int x, unsigned& fbits) {
    float2 e;
    e.x = pf[x].x; e.y = pf[x].y;
    int p = __float_as_int(e.y);
    while (p != x) {
        float2 ep;
        ep.x = pf[p].x; ep.y = pf[p].y;
        int gp = __float_as_int(ep.y);
        if (gp != p) { pf[x].x = ep.x; pf[x].y = ep.y; }   // path halving
        x = p; e = ep; p = gp;
    }
    fbits = __float_as_uint(e.x);
    return x;
}

__device__ __forceinline__ unsigned long long vkey(const float* fv, int u) {
    return (((unsigned long long)__float_as_uint(fv[u])) << 10) | (unsigned long long)u;
}

__global__ __launch_bounds__(512) void topo_kernel(
        const float* __restrict__ fv_g, float* __restrict__ feat,
        int* __restrict__ cnt_g,
        const float* __restrict__ wg1, const float* __restrict__ bg1,
        const float* __restrict__ wg2, const float* __restrict__ bg2,
        const float* __restrict__ fcw, const float* __restrict__ fcb,
        float* __restrict__ out) {
    __shared__ unsigned long long skey64[NPAD];
    __shared__ float fv[N];
    __shared__ float dv[N];
    __shared__ float2 pf_s[N];
    __shared__ short pd[N];
    __shared__ short labA[N], labB[N];
    __shared__ unsigned ev[MEDGE];
    __shared__ int wsum[16];
    __shared__ float xc[B * 100];
    volatile float2* pf = pf_s;
    const int prob = blockIdx.x, tid = threadIdx.x, lane = tid & 63, wid = tid >> 6;

    for (int j = tid; j < NPAD; j += 512) {
        if (j < N) {
            float v = fv_g[prob * N + j];
            fv[j] = v;
            skey64[j] = (((unsigned long long)__float_as_uint(v)) << 10) | (unsigned long long)j;
        } else {
            skey64[j] = ~0ull;
        }
    }
    __syncthreads();
    // ---- hybrid bitonic: regs + shuffles; LDS only for j>=128 ----
    {
        const int idx0 = wid * 128 + lane;
        const int idx1 = idx0 + 64;
        unsigned long long e0 = skey64[idx0];
        unsigned long long e1 = skey64[idx1];
        for (int k = 2; k <= NPAD; k <<= 1) {
            for (int j = k >> 1; j > 0; j >>= 1) {
                if (j >= 128) {
                    skey64[idx0] = e0; skey64[idx1] = e1;
                    __syncthreads();
                    unsigned long long p0 = skey64[idx0 ^ j];
                    unsigned long long p1 = skey64[idx1 ^ j];
                    bool up0 = ((idx0 & k) == 0), lo0 = ((idx0 & j) == 0);
                    bool up1 = ((idx1 & k) == 0), lo1 = ((idx1 & j) == 0);
                    e0 = (up0 == lo0) ? (p0 < e0 ? p0 : e0) : (p0 > e0 ? p0 : e0);
                    e1 = (up1 == lo1) ? (p1 < e1 ? p1 : e1) : (p1 > e1 ? p1 : e1);
                    __syncthreads();
                } else if (j == 64) {
                    bool up = ((idx0 & k) == 0);   // idx0,idx1 share bit k (k>=128)
                    unsigned long long mn = e0 < e1 ? e0 : e1;
                    unsigned long long mx = e0 < e1 ? e1 : e0;
                    e0 = up ? mn : mx; e1 = up ? mx : mn;
                } else {
                    unsigned long long p0 = shfl_xor64(e0, j);
                    unsigned long long p1 = shfl_xor64(e1, j);
                    bool lo = ((lane & j) == 0);
                    bool up0 = ((idx0 & k) == 0);
                    bool up1 = ((idx1 & k) == 0);
                    e0 = (up0 == lo) ? (p0 < e0 ? p0 : e0) : (p0 > e0 ? p0 : e0);
                    e1 = (up1 == lo) ? (p1 < e1 ? p1 : e1) : (p1 > e1 ? p1 : e1);
                }
            }
        }
        skey64[idx0] = e0; skey64[idx1] = e1;
    }
    __syncthreads();
    // ---- pf/pd init + descent pointers (min-key neighbor) ----
    for (int v = tid; v < N; v += 512) {
        pf_s[v] = make_float2(fv[v], __int_as_float(v));
        pd[v] = (short)v;
        int row = v / H, col = v % H;
        unsigned long long bk = vkey(fv, v); int bestn = v;
        if (row > 0)     { unsigned long long kk = vkey(fv, v - H); if (kk < bk) { bk = kk; bestn = v - H; } }
        if (row < H - 1) { unsigned long long kk = vkey(fv, v + H); if (kk < bk) { bk = kk; bestn = v + H; } }
        if (col > 0)     { unsigned long long kk = vkey(fv, v - 1); if (kk < bk) { bk = kk; bestn = v - 1; } }
        if (col < H - 1) { unsigned long long kk = vkey(fv, v + 1); if (kk < bk) { bk = kk; bestn = v + 1; } }
        labA[v] = (short)bestn;
    }
    __syncthreads();
    // ---- pointer jumping to basin minima ----
    {
        short* lsrc = labA; short* ldst = labB;
        for (int it = 0; it < 10; ++it) {
            for (int v = tid; v < N; v += 512) ldst[v] = lsrc[(int)lsrc[v]];
            __syncthreads();
            short* t = lsrc; lsrc = ldst; ldst = t;
        }
    }
    const short* lab = labA;   // 10 swaps -> back in labA
    // ---- candidates: thread owns sorted ranks 2t, 2t+1 (order-correct) ----
    int deg[2]; int vq[2], lvq[2];
    #pragma unroll
    for (int h = 0; h < 2; ++h) {
        int r = 2 * tid + h;
        deg[h] = 0;
        int v = (int)(skey64[r] & 1023ull);
        vq[h] = v;
        if (v < N) {
            unsigned long long kv = skey64[r];
            int row = v / H, col = v % H;
            int lv = (int)lab[v]; lvq[h] = lv;
            if (row > 0     && vkey(fv, v - H) < kv && (int)lab[v - H] != lv) deg[h]++;
            if (row < H - 1 && vkey(fv, v + H) < kv && (int)lab[v + H] != lv) deg[h]++;
            if (col > 0     && vkey(fv, v - 1) < kv && (int)lab[v - 1] != lv) deg[h]++;
            if (col < H - 1 && vkey(fv, v + 1) < kv && (int)lab[v + 1] != lv) deg[h]++;
        }
    }
    int tot = deg[0] + deg[1];
    int inc = tot;
    #pragma unroll
    for (int off = 1; off < 64; off <<= 1) {
        int n = __shfl_up(inc, off, 64);
        if (lane >= off) inc += n;
    }
    if (lane == 63) wsum[wid] = inc;
    __syncthreads();
    if (wid == 0 && lane < 8) {
        int v = wsum[lane];
        #pragma unroll
        for (int off = 1; off < 8; off <<= 1) {
            int n = __shfl_up(v, off, 64);
            if (lane >= off) v += n;
        }
        wsum[8 + lane] = v;
    }
    __syncthreads();
    int base = (wid ? wsum[8 + wid - 1] : 0) + inc - tot;
    const int mc = wsum[8 + 7];
    #pragma unroll
    for (int h = 0; h < 2; ++h) {
        int r = 2 * tid + h; int v = vq[h];
        if (v < N && deg[h]) {
            unsigned long long kv = skey64[r];
            int row = v / H, col = v % H;
            int lv = lvq[h];
            int nbs[4] = { v - H, v + H, v - 1, v + 1 };
            bool val[4] = { row > 0, row < H - 1, col > 0, col < H - 1 };
            int pos = base;
            #pragma unroll
            for (int k4 = 0; k4 < 4; ++k4) {
                if (val[k4] && vkey(fv, nbs[k4]) < kv && (int)lab[nbs[k4]] != lv) {
                    ev[pos++] = (unsigned)v | ((unsigned)lv << 10)
                              | ((unsigned)(int)lab[nbs[k4]] << 20);
                }
            }
        }
        base += deg[h];
    }
    __syncthreads();

    // ---- wave-0 tiny UF over candidates (ballot resolve) ----
    if (tid < 64) {
        const int nch = (mc + 63) >> 6;
        for (int c = 0; c < nch; ++c) {
            int idx = c * 64 + lane;
            unsigned e = (idx < mc) ? ev[idx] : 0u;
            const int uu = (int)(e & 1023u);
            const int bu = (int)((e >> 10) & 1023u);
            const int bw = (int)((e >> 20) & 1023u);
            unsigned fa, fb;
            int ra = pf_find(pf, bu, fa);
            int rb = pf_find(pf, bw, fb);
            int myL = -1, myW = 0; unsigned myWF = 0;
            unsigned long long mask = __ballot(ra != rb);
            while (mask) {
                int j = __builtin_ctzll(mask);
                mask &= mask - 1;
                int s_a = __builtin_amdgcn_readlane(ra, j);
                int s_b = __builtin_amdgcn_readlane(rb, j);
                if (s_a != s_b) {          // uniform
                    unsigned s_fa = (unsigned)__builtin_amdgcn_readlane((int)fa, j);
                    unsigned s_fb = (unsigned)__builtin_amdgcn_readlane((int)fb, j);
                    bool nw = (s_fb < s_fa) || (s_fb == s_fa && s_b < s_a);
                    int s_w = nw ? s_b : s_a;
                    int s_l = nw ? s_a : s_b;
                    unsigned s_wf = nw ? s_fb : s_fa;
                    bool me = (lane == j);
                    myL  = me ? s_l  : myL;
                    myW  = me ? s_w  : myW;
                    myWF = me ? s_wf : myWF;
                    bool ha = (ra == s_l);
                    ra = ha ? s_w : ra; fa = ha ? s_wf : fa;
                    bool hb = (rb == s_l);
                    rb = hb ? s_w : rb; fb = hb ? s_wf : fb;
                }
            }
            if (myL >= 0) {                // losers distinct -> race-free
                pd[myL] = (short)uu;
                pf[myL].x = __uint_as_float(myWF);
                pf[myL].y = __int_as_float(myW);
            }
            __builtin_amdgcn_sched_barrier(0);
        }
        if (lane == 0) {
            unsigned dummy;
            int vmax = (int)(skey64[N - 1] & 1023ull);
            int g = pf_find(pf, (int)lab[vmax], dummy);
            pd[g] = (short)vmax;
        }
    }
    __syncthreads();

    // ---- death values, then landscapes with linear reads ----
    for (int j = tid; j < N; j += 512) dv[j] = fv[(int)pd[j]];
    __syncthreads();
    for (int t = wid; t < T; t += 8) {
        float tval = (t == T - 1) ? 80.0f : (1.0f + (float)t * (79.0f / 24.0f));
        float m1 = 0.f, m2 = 0.f;
        for (int i = lane; i < N; i += 64) {
            float tv = fminf(tval - fv[i], dv[i] - tval);
            tv = fmaxf(tv, 0.f);
            float lo = fminf(tv, m1);
            m1 = fmaxf(tv, m1);
            m2 = fmaxf(m2, lo);
        }
        #pragma unroll
        for (int off = 32; off > 0; off >>= 1) {
            float o1 = __shfl_down(m1, off, 64);
            float o2 = __shfl_down(m2, off, 64);
            float hi = fmaxf(m1, o1);
            float lo = fminf(m1, o1);
            m2 = fmaxf(fmaxf(m2, o2), lo);
            m1 = hi;
        }
        if (lane == 0) {
            feat[prob * 50 + t]     = m1;
            feat[prob * 50 + T + t] = m2;
        }
    }

    // ---- atomic tail: last block to finish runs the head ----
    __syncthreads();               // all feat writes issued
    if (tid == 0) {
        __threadfence();           // release: feat visible device-wide
        int old = atomicAdd(cnt_g, 1);
        wsum[0] = (old == 63) ? 1 : 0;
    }
    __syncthreads();
    if (wsum[0]) {
        __threadfence();           // acquire: other blocks' feat visible
        for (int e = tid; e < B * 100; e += 512) {
            int b = e / 100, j = e % 100;
            const float* fp; const float* wrow; float bias;
            if (j < 50) { fp = feat + b * 50;       wrow = wg1 + j * 50;        bias = bg1[j]; }
            else        { fp = feat + (B + b) * 50; wrow = wg2 + (j - 50) * 50; bias = bg2[j - 50]; }
            float acc = bias;
            for (int q = 0; q < 50; ++q) acc += fp[q] * wrow[q];
            xc[e] = acc;
        }
        __syncthreads();
        for (int j = tid; j < 100; j += 512) {
            float s = 0.f;
            for (int b = 0; b < B; ++b) s += fabsf(xc[b * 100 + j]);
            out[320 + j] = s;
        }
        for (int e = tid; e < 320; e += 512) {
            int b = e / 10, o = e % 10;
            float acc = fcb[o];
            for (int j = 0; j < 100; ++j)
                acc += fmaxf(xc[b * 100 + j], 0.f) * fcw[o * 100 + j];
            out[e] = acc;
        }
    }
}

extern "C" void kernel_launch(void* const* d_in, const int* in_sizes, int n_in,
                              void* d_out, int out_size, void* d_ws, size_t ws_size,
                              hipStream_t stream) {
    (void)in_sizes; (void)n_in; (void)out_size; (void)ws_size;
    const float* x   = (const float*)d_in[0];
    const float* wg1 = (const float*)d_in[1];
    const float* bg1 = (const float*)d_in[2];
    const float* wg2 = (const float*)d_in[3];
    const float* bg2 = (const float*)d_in[4];
    const float* fcw = (const float*)d_in[5];
    const float* fcb = (const float*)d_in[6];
    float* out = (float*)d_out;

    char* ws = (char*)d_ws;
    float*          d2s    = (float*)ws;                                    // 784*784 f32
    unsigned short* sidx   = (unsigned short*)(ws + (size_t)N * N * 4);     // 784*784 u16
    float*          fv_g   = (float*)(ws + (size_t)N * N * 6);              // 64*784 f32
    float*          feat   = (float*)(ws + (size_t)N * N * 6 + 64 * N * 4); // 64*50 f32
    int*            cnt_g  = (int*)(ws + (size_t)N * N * 6 + 64 * N * 4 + 64 * 50 * 4);

    build_lists_kernel<<<dim3(N), dim3(256), 0, stream>>>(d2s, sidx, cnt_g);
    dtm_kernel<<<dim3(256), dim3(256), 0, stream>>>(x, d2s, sidx, fv_g);
    topo_kernel<<<dim3(64), dim3(512), 0, stream>>>(fv_g, feat, cnt_g,
                                                    wg1, bg1, wg2, bg2, fcw, fcb, out);
}

// Round 16
// 61.481 us; speedup vs baseline: 1.3513x; 1.2133x over previous
//
#include <hip/hip_runtime.h>
#include <math.h>

#define H 28
#define N 784
#define B 32
#define T 25
#define NPAD 1024
#define CH 16
#define MEDGE 1536
#define NOFF 3025   // 55*55 lattice offsets

// ============================================================
// Compile-time ordered offset table: sorted by (integer d2, dr, dc).
// Row-independent neighbor order (validated rounds 10-15, absmax 0).
// ============================================================
struct OffTable { unsigned short v[NOFF]; };
constexpr OffTable make_offs() {
    OffTable t{};
    int cnt[1459] = {};
    for (int dr = -27; dr <= 27; ++dr)
        for (int dc = -27; dc <= 27; ++dc)
            cnt[dr * dr + dc * dc]++;
    int base[1459] = {};
    int acc = 0;
    for (int d = 0; d <= 1458; ++d) { base[d] = acc; acc += cnt[d]; }
    for (int dr = -27; dr <= 27; ++dr)
        for (int dc = -27; dc <= 27; ++dc) {
            int d2 = dr * dr + dc * dc;
            t.v[base[d2]++] = (unsigned short)(((dr + 27) << 6) | (dc + 27));
        }
    return t;
}
__device__ __constant__ OffTable OFF_TABLE = make_offs();

// ---- numpy linspace replication (float64) ----
__device__ __forceinline__ double coord_r_f(int i) {
    if (i == H - 1) return 0.0;
    return 224.0 + (double)i * ((0.0 - 224.0) / 27.0);
}
__device__ __forceinline__ double coord_c_f(int j) {
    if (j == H - 1) return 224.0;
    return (double)j * (224.0 / 27.0);
}

__device__ __forceinline__ unsigned long long shfl_xor64(unsigned long long v, int m) {
    int lo = __shfl_xor((int)(unsigned)v, m, 64);
    int hi = __shfl_xor((int)(unsigned)(v >> 32), m, 64);
    return ((unsigned long long)(unsigned)hi << 32) | (unsigned)lo;
}

// ============================================================
// K1: per-row filter-compaction, 3 barriers (r13, passing).
// Also zeroes the topo completion counter (used 2 kernels later).
// ============================================================
__global__ __launch_bounds__(256) void build_lists_kernel(
        float* __restrict__ d2s, unsigned short* __restrict__ sidx,
        int* __restrict__ cnt_g) {
    __shared__ double crtab[H], cctab[H];
    __shared__ float cd2[N];
    __shared__ unsigned short cjj[N];
    __shared__ unsigned long long wmask[48];
    __shared__ int wbase[48];
    const int i = blockIdx.x, tid = threadIdx.x, lane = tid & 63;
    const int w = tid >> 6;
    if (i == 0 && tid == 0) *cnt_g = 0;
    if (tid < H) { crtab[tid] = coord_r_f(tid); cctab[tid] = coord_c_f(tid); }
    const int ri = i / H, ci = i % H;
    unsigned validm = 0;
    #pragma unroll
    for (int c = 0; c < 12; ++c) {
        int p = c * 256 + tid;
        bool valid = false;
        if (p < NOFF) {
            unsigned o = OFF_TABLE.v[p];
            int rj = ri + (int)(o >> 6) - 27;
            int cj_ = ci + (int)(o & 63u) - 27;
            valid = ((unsigned)rj < (unsigned)H) && ((unsigned)cj_ < (unsigned)H);
        }
        unsigned long long m = __ballot(valid);
        if (valid) validm |= (1u << c);
        if (lane == 0) wmask[c * 4 + w] = m;
    }
    __syncthreads();
    if (w == 0) {
        int cnt = (lane < 48) ? __popcll(wmask[lane]) : 0;
        int inc = cnt;
        #pragma unroll
        for (int off = 1; off < 64; off <<= 1) {
            int n = __shfl_up(inc, off, 64);
            if (lane >= off) inc += n;
        }
        if (lane < 48) wbase[lane] = inc - cnt;   // exclusive prefix
    }
    __syncthreads();
    const double rri = crtab[ri], cci = cctab[ci];
    const unsigned long long ltmask = (lane == 0) ? 0ull : (~0ull >> (64 - lane));
    #pragma unroll
    for (int c = 0; c < 12; ++c) {
        if (validm & (1u << c)) {
            int p = c * 256 + tid;
            unsigned o = OFF_TABLE.v[p];
            int rj = ri + (int)(o >> 6) - 27;
            int cj_ = ci + (int)(o & 63u) - 27;
            int pos = wbase[c * 4 + w] + __popcll(wmask[c * 4 + w] & ltmask);
            double ddr = rri - crtab[rj];
            double ddc = cci - cctab[cj_];
            cd2[pos] = (float)(ddr * ddr + ddc * ddc);
            cjj[pos] = (unsigned short)(rj * H + cj_);
        }
    }
    __syncthreads();
    for (int k = tid; k < N; k += 256) {
        d2s[(size_t)i * N + k]  = cd2[k];
        sidx[(size_t)i * N + k] = cjj[k];
    }
}

// ============================================================
// K2: DTM. 4 blocks per problem (256 blocks), 1 pixel/thread,
// early-exit walk of the row-major presorted list. (r12/r13, passing)
// ============================================================
__global__ __launch_bounds__(256) void dtm_kernel(
        const float* __restrict__ x,
        const float* __restrict__ d2s,
        const unsigned short* __restrict__ sidx,
        float* __restrict__ fv_g) {
    __shared__ float lw[N];
    __shared__ float red[256];
    const int blk = blockIdx.x;
    const int prob = blk >> 2, quarter = blk & 3;
    const int b = prob & 31, mi = prob >> 5;
    const float m0 = mi ? 0.2f : 0.05f;
    const int tid = threadIdx.x;
    float s = 0.f;
    for (int j = tid; j < N; j += 256) { float v = x[b * N + j]; lw[j] = v; s += v; }
    red[tid] = s;
    __syncthreads();
    for (int off = 128; off > 0; off >>= 1) {
        if (tid < off) red[tid] += red[tid + off];
        __syncthreads();
    }
    const float m0W = m0 * red[0];
    if (tid < 196) {
        const int i = quarter * 196 + tid;
        const float* d2r = d2s + (size_t)i * N;
        const unsigned short* idr = sidx + (size_t)i * N;
        float cum = 0.f, acc = 0.f;
        for (int k0 = 0; k0 < N; k0 += CH) {
            float d2c[CH]; int idc[CH];
            #pragma unroll
            for (int c = 0; c < CH; ++c) { d2c[c] = d2r[k0 + c]; idc[c] = idr[k0 + c]; }
            float swc[CH];
            #pragma unroll
            for (int c = 0; c < CH; ++c) swc[c] = lw[idc[c]];
            #pragma unroll
            for (int c = 0; c < CH; ++c) {
                float rem = m0W - cum;
                float contrib = fminf(fmaxf(rem, 0.f), swc[c]);
                acc += contrib * d2c[c];
                cum += swc[c];
            }
            if (cum >= m0W) break;   // all later contribs are exactly 0
        }
        fv_g[prob * N + i] = sqrtf(fmaxf(acc / m0W, 1e-12f));
    }
}

// ============================================================
// K3: topo + per-block xc row (50x50 GEMV on in-LDS feat) +
// light atomic-tail (signal + fc only).
// ============================================================
__device__ __forceinline__ int pf_find(volatile float2* pf, int x, unsigned& fbits) {
    float2 e;
    e.x = pf[x].x; e.y = pf[x].y;
    int p = __float_as_int(e.y);
    while (p != x) {
        float2 ep;
        ep.x = pf[p].x; ep.y = pf[p].y;
        int gp = __float_as_int(ep.y);
        if (gp != p) { pf[x].x = ep.x; pf[x].y = ep.y; }   // path halving
        x = p; e = ep; p = gp;
    }
    fbits = __float_as_uint(e.x);
    return x;
}

__device__ __forceinline__ unsigned long long vkey(const float* fv, int u) {
    return (((unsigned long long)__float_as_uint(fv[u])) << 10) | (unsigned long long)u;
}

__global__ __launch_bounds__(512) void topo_kernel(
        const float* __restrict__ fv_g, float* __restrict__ xc_g,
        int* __restrict__ cnt_g,
        const float* __restrict__ wg1, const float* __restrict__ bg1,
        const float* __restrict__ wg2, const float* __restrict__ bg2,
        const float* __restrict__ fcw, const float* __restrict__ fcb,
        float* __restrict__ out) {
    __shared__ unsigned long long skey64[NPAD];
    __shared__ float fv[N];
    __shared__ float dv[N];
    __shared__ float2 pf_s[N];
    __shared__ short pd[N];
    __shared__ short labA[N], labB[N];
    __shared__ unsigned ev[MEDGE];
    __shared__ int wsum[16];
    __shared__ float feat_s[50];
    __shared__ float xc_s[B * 100];
    volatile float2* pf = pf_s;
    const int prob = blockIdx.x, tid = threadIdx.x, lane = tid & 63, wid = tid >> 6;

    for (int j = tid; j < NPAD; j += 512) {
        if (j < N) {
            float v = fv_g[prob * N + j];
            fv[j] = v;
            skey64[j] = (((unsigned long long)__float_as_uint(v)) << 10) | (unsigned long long)j;
        } else {
            skey64[j] = ~0ull;
        }
    }
    __syncthreads();
    // ---- hybrid bitonic: regs + shuffles; LDS only for j>=128 ----
    {
        const int idx0 = wid * 128 + lane;
        const int idx1 = idx0 + 64;
        unsigned long long e0 = skey64[idx0];
        unsigned long long e1 = skey64[idx1];
        for (int k = 2; k <= NPAD; k <<= 1) {
            for (int j = k >> 1; j > 0; j >>= 1) {
                if (j >= 128) {
                    skey64[idx0] = e0; skey64[idx1] = e1;
                    __syncthreads();
                    unsigned long long p0 = skey64[idx0 ^ j];
                    unsigned long long p1 = skey64[idx1 ^ j];
                    bool up0 = ((idx0 & k) == 0), lo0 = ((idx0 & j) == 0);
                    bool up1 = ((idx1 & k) == 0), lo1 = ((idx1 & j) == 0);
                    e0 = (up0 == lo0) ? (p0 < e0 ? p0 : e0) : (p0 > e0 ? p0 : e0);
                    e1 = (up1 == lo1) ? (p1 < e1 ? p1 : e1) : (p1 > e1 ? p1 : e1);
                    __syncthreads();
                } else if (j == 64) {
                    bool up = ((idx0 & k) == 0);   // idx0,idx1 share bit k (k>=128)
                    unsigned long long mn = e0 < e1 ? e0 : e1;
                    unsigned long long mx = e0 < e1 ? e1 : e0;
                    e0 = up ? mn : mx; e1 = up ? mx : mn;
                } else {
                    unsigned long long p0 = shfl_xor64(e0, j);
                    unsigned long long p1 = shfl_xor64(e1, j);
                    bool lo = ((lane & j) == 0);
                    bool up0 = ((idx0 & k) == 0);
                    bool up1 = ((idx1 & k) == 0);
                    e0 = (up0 == lo) ? (p0 < e0 ? p0 : e0) : (p0 > e0 ? p0 : e0);
                    e1 = (up1 == lo) ? (p1 < e1 ? p1 : e1) : (p1 > e1 ? p1 : e1);
                }
            }
        }
        skey64[idx0] = e0; skey64[idx1] = e1;
    }
    __syncthreads();
    // ---- pf/pd init + descent pointers (min-key neighbor) ----
    for (int v = tid; v < N; v += 512) {
        pf_s[v] = make_float2(fv[v], __int_as_float(v));
        pd[v] = (short)v;
        int row = v / H, col = v % H;
        unsigned long long bk = vkey(fv, v); int bestn = v;
        if (row > 0)     { unsigned long long kk = vkey(fv, v - H); if (kk < bk) { bk = kk; bestn = v - H; } }
        if (row < H - 1) { unsigned long long kk = vkey(fv, v + H); if (kk < bk) { bk = kk; bestn = v + H; } }
        if (col > 0)     { unsigned long long kk = vkey(fv, v - 1); if (kk < bk) { bk = kk; bestn = v - 1; } }
        if (col < H - 1) { unsigned long long kk = vkey(fv, v + 1); if (kk < bk) { bk = kk; bestn = v + 1; } }
        labA[v] = (short)bestn;
    }
    __syncthreads();
    // ---- pointer jumping to basin minima ----
    {
        short* lsrc = labA; short* ldst = labB;
        for (int it = 0; it < 10; ++it) {
            for (int v = tid; v < N; v += 512) ldst[v] = lsrc[(int)lsrc[v]];
            __syncthreads();
            short* t = lsrc; lsrc = ldst; ldst = t;
        }
    }
    const short* lab = labA;   // 10 swaps -> back in labA
    // ---- candidates: thread owns sorted ranks 2t, 2t+1 (order-correct) ----
    int deg[2]; int vq[2], lvq[2];
    #pragma unroll
    for (int h = 0; h < 2; ++h) {
        int r = 2 * tid + h;
        deg[h] = 0;
        int v = (int)(skey64[r] & 1023ull);
        vq[h] = v;
        if (v < N) {
            unsigned long long kv = skey64[r];
            int row = v / H, col = v % H;
            int lv = (int)lab[v]; lvq[h] = lv;
            if (row > 0     && vkey(fv, v - H) < kv && (int)lab[v - H] != lv) deg[h]++;
            if (row < H - 1 && vkey(fv, v + H) < kv && (int)lab[v + H] != lv) deg[h]++;
            if (col > 0     && vkey(fv, v - 1) < kv && (int)lab[v - 1] != lv) deg[h]++;
            if (col < H - 1 && vkey(fv, v + 1) < kv && (int)lab[v + 1] != lv) deg[h]++;
        }
    }
    int tot = deg[0] + deg[1];
    int inc = tot;
    #pragma unroll
    for (int off = 1; off < 64; off <<= 1) {
        int n = __shfl_up(inc, off, 64);
        if (lane >= off) inc += n;
    }
    if (lane == 63) wsum[wid] = inc;
    __syncthreads();
    if (wid == 0 && lane < 8) {
        int v = wsum[lane];
        #pragma unroll
        for (int off = 1; off < 8; off <<= 1) {
            int n = __shfl_up(v, off, 64);
            if (lane >= off) v += n;
        }
        wsum[8 + lane] = v;
    }
    __syncthreads();
    int base = (wid ? wsum[8 + wid - 1] : 0) + inc - tot;
    const int mc = wsum[8 + 7];
    #pragma unroll
    for (int h = 0; h < 2; ++h) {
        int r = 2 * tid + h; int v = vq[h];
        if (v < N && deg[h]) {
            unsigned long long kv = skey64[r];
            int row = v / H, col = v % H;
            int lv = lvq[h];
            int nbs[4] = { v - H, v + H, v - 1, v + 1 };
            bool val[4] = { row > 0, row < H - 1, col > 0, col < H - 1 };
            int pos = base;
            #pragma unroll
            for (int k4 = 0; k4 < 4; ++k4) {
                if (val[k4] && vkey(fv, nbs[k4]) < kv && (int)lab[nbs[k4]] != lv) {
                    ev[pos++] = (unsigned)v | ((unsigned)lv << 10)
                              | ((unsigned)(int)lab[nbs[k4]] << 20);
                }
            }
        }
        base += deg[h];
    }
    __syncthreads();

    // ---- wave-0 tiny UF over candidates (ballot resolve) ----
    if (tid < 64) {
        const int nch = (mc + 63) >> 6;
        for (int c = 0; c < nch; ++c) {
            int idx = c * 64 + lane;
            unsigned e = (idx < mc) ? ev[idx] : 0u;
            const int uu = (int)(e & 1023u);
            const int bu = (int)((e >> 10) & 1023u);
            const int bw = (int)((e >> 20) & 1023u);
            unsigned fa, fb;
            int ra = pf_find(pf, bu, fa);
            int rb = pf_find(pf, bw, fb);
            int myL = -1, myW = 0; unsigned myWF = 0;
            unsigned long long mask = __ballot(ra != rb);
            while (mask) {
                int j = __builtin_ctzll(mask);
                mask &= mask - 1;
                int s_a = __builtin_amdgcn_readlane(ra, j);
                int s_b = __builtin_amdgcn_readlane(rb, j);
                if (s_a != s_b) {          // uniform
                    unsigned s_fa = (unsigned)__builtin_amdgcn_readlane((int)fa, j);
                    unsigned s_fb = (unsigned)__builtin_amdgcn_readlane((int)fb, j);
                    bool nw = (s_fb < s_fa) || (s_fb == s_fa && s_b < s_a);
                    int s_w = nw ? s_b : s_a;
                    int s_l = nw ? s_a : s_b;
                    unsigned s_wf = nw ? s_fb : s_fa;
                    bool me = (lane == j);
                    myL  = me ? s_l  : myL;
                    myW  = me ? s_w  : myW;
                    myWF = me ? s_wf : myWF;
                    bool ha = (ra == s_l);
                    ra = ha ? s_w : ra; fa = ha ? s_wf : fa;
                    bool hb = (rb == s_l);
                    rb = hb ? s_w : rb; fb = hb ? s_wf : fb;
                }
            }
            if (myL >= 0) {                // losers distinct -> race-free
                pd[myL] = (short)uu;
                pf[myL].x = __uint_as_float(myWF);
                pf[myL].y = __int_as_float(myW);
            }
            __builtin_amdgcn_sched_barrier(0);
        }
        if (lane == 0) {
            unsigned dummy;
            int vmax = (int)(skey64[N - 1] & 1023ull);
            int g = pf_find(pf, (int)lab[vmax], dummy);
            pd[g] = (short)vmax;
        }
    }
    __syncthreads();

    // ---- death values, then landscapes (feat row kept in LDS) ----
    for (int j = tid; j < N; j += 512) dv[j] = fv[(int)pd[j]];
    __syncthreads();
    for (int t = wid; t < T; t += 8) {
        float tval = (t == T - 1) ? 80.0f : (1.0f + (float)t * (79.0f / 24.0f));
        float m1 = 0.f, m2 = 0.f;
        for (int i = lane; i < N; i += 64) {
            float tv = fminf(tval - fv[i], dv[i] - tval);
            tv = fmaxf(tv, 0.f);
            float lo = fminf(tv, m1);
            m1 = fmaxf(tv, m1);
            m2 = fmaxf(m2, lo);
        }
        #pragma unroll
        for (int off = 32; off > 0; off >>= 1) {
            float o1 = __shfl_down(m1, off, 64);
            float o2 = __shfl_down(m2, off, 64);
            float hi = fmaxf(m1, o1);
            float lo = fminf(m1, o1);
            m2 = fmaxf(fmaxf(m2, o2), lo);
            m1 = hi;
        }
        if (lane == 0) {
            feat_s[t]     = m1;
            feat_s[T + t] = m2;
        }
    }
    __syncthreads();

    // ---- per-block xc row: xc[prob] = feat_row @ wg.T + bg (same FP order as ref head) ----
    {
        const float* wgp = (prob < 32) ? wg1 : wg2;
        const float* bgp = (prob < 32) ? bg1 : bg2;
        if (tid < 50) {
            float acc = bgp[tid];
            const float* wrow = wgp + tid * 50;
            for (int q = 0; q < 50; ++q) acc += feat_s[q] * wrow[q];
            xc_g[prob * 50 + tid] = acc;
        }
    }

    // ---- light atomic tail: last block runs signal + fc ----
    __syncthreads();               // xc writes issued
    if (tid == 0) {
        __threadfence();           // release: xc visible device-wide
        int old = atomicAdd(cnt_g, 1);
        wsum[0] = (old == 63) ? 1 : 0;
    }
    __syncthreads();
    if (wsum[0]) {
        __threadfence();           // acquire: other blocks' xc visible
        for (int e = tid; e < B * 100; e += 512) {
            int b = e / 100, j = e % 100;
            xc_s[e] = (j < 50) ? xc_g[b * 50 + j] : xc_g[(32 + b) * 50 + (j - 50)];
        }
        __syncthreads();
        for (int j = tid; j < 100; j += 512) {
            float s = 0.f;
            for (int b = 0; b < B; ++b) s += fabsf(xc_s[b * 100 + j]);
            out[320 + j] = s;
        }
        for (int e = tid; e < 320; e += 512) {
            int b = e / 10, o = e % 10;
            float acc = fcb[o];
            for (int j = 0; j < 100; ++j)
                acc += fmaxf(xc_s[b * 100 + j], 0.f) * fcw[o * 100 + j];
            out[e] = acc;
        }
    }
}

extern "C" void kernel_launch(void* const* d_in, const int* in_sizes, int n_in,
                              void* d_out, int out_size, void* d_ws, size_t ws_size,
                              hipStream_t stream) {
    (void)in_sizes; (void)n_in; (void)out_size; (void)ws_size;
    const float* x   = (const float*)d_in[0];
    const float* wg1 = (const float*)d_in[1];
    const float* bg1 = (const float*)d_in[2];
    const float* wg2 = (const float*)d_in[3];
    const float* bg2 = (const float*)d_in[4];
    const float* fcw = (const float*)d_in[5];
    const float* fcb = (const float*)d_in[6];
    float* out = (float*)d_out;

    char* ws = (char*)d_ws;
    float*          d2s    = (float*)ws;                                    // 784*784 f32
    unsigned short* sidx   = (unsigned short*)(ws + (size_t)N * N * 4);     // 784*784 u16
    float*          fv_g   = (float*)(ws + (size_t)N * N * 6);              // 64*784 f32
    float*          xc_g   = (float*)(ws + (size_t)N * N * 6 + 64 * N * 4); // 64*50 f32
    int*            cnt_g  = (int*)(ws + (size_t)N * N * 6 + 64 * N * 4 + 64 * 50 * 4);

    build_lists_kernel<<<dim3(N), dim3(256), 0, stream>>>(d2s, sidx, cnt_g);
    dtm_kernel<<<dim3(256), dim3(256), 0, stream>>>(x, d2s, sidx, fv_g);
    topo_kernel<<<dim3(64), dim3(512), 0, stream>>>(fv_g, xc_g, cnt_g,
                                                    wg1, bg1, wg2, bg2, fcw, fcb, out);
}